// Round 4
// baseline (425.156 us; speedup 1.0000x reference)
//
#include <hip/hip_runtime.h>
#include <hip/hip_fp16.h>

#define DD 192
#define HH 192
#define WW 192
#define NVOX (DD * HH * WW)

#define TX 16
#define TY 16
#define TZ 8
#define HLO 8
// staged region (fp16): x 32 [-8,+24), y 33 [-8,+25), z 25 [-8,+17)
#define RSX 32
#define RSY 33
#define RSZ 25
#define SLAB (RSY * RSX)     // 1056
#define RTOT (RSZ * SLAB)    // 26400 halves = 52.8 KB
#define NTHREADS 512
#define NBLK ((WW / TX) * (HH / TY) * (DD / TZ))   // 12*12*24 = 3456

__global__ __launch_bounds__(NTHREADS, 6) void warp_mse_tiled(
    const float* __restrict__ mov,
    const float* __restrict__ vf,
    const float* __restrict__ fix,
    const int* __restrict__ mask,
    float* __restrict__ acc,   // acc[0]=sum(sq*m), acc[1]=sum(m), acc[2]=done counter
    float* __restrict__ out)
{
    __shared__ __half smov[RTOT];
    __shared__ float s_sq[8], s_cnt[8];

    const int tid = threadIdx.x;
    const int bx0 = blockIdx.x * TX;
    const int by0 = blockIdx.y * TY;
    const int bz0 = blockIdx.z * TZ;
    const int z_lo = bz0 - HLO, y_lo = by0 - HLO, x_lo = bx0 - HLO;

    // ---- stage mov region into LDS as fp16, zero-padded outside volume ----
    // Each thread owns up to 3 (ry,rx) columns; all 25 z-loads of a column are
    // issued into registers before any LDS write -> 25-deep MLP.
    #pragma unroll
    for (int cb = 0; cb < 3; ++cb) {
        const int c = tid + cb * NTHREADS;
        if (c < SLAB) {
            const int ry = c >> 5;          // c / RSX
            const int rx = c & 31;          // c % RSX
            const int gy = y_lo + ry, gx = x_lo + rx;
            const bool vxy = ((unsigned)gy < HH) & ((unsigned)gx < WW);
            float vals[RSZ];
            #pragma unroll
            for (int rz = 0; rz < RSZ; ++rz) {
                const int gz = z_lo + rz;
                vals[rz] = (vxy && (unsigned)gz < DD)
                             ? mov[(gz * HH + gy) * WW + gx] : 0.0f;
            }
            #pragma unroll
            for (int rz = 0; rz < RSZ; ++rz)
                smov[rz * SLAB + c] = __float2half(vals[rz]);
        }
    }
    __syncthreads();

    // ---- compute: each thread handles an x-quad of 4 voxels ----
    const int lxg = (tid & 3) * 4;
    const int ly  = (tid >> 2) & 15;
    const int lz  = tid >> 6;              // 0..7
    const int gz = bz0 + lz;
    const int gy = by0 + ly;
    const int gx0 = bx0 + lxg;
    const int base = (gz * HH + gy) * WW + gx0;

    const float4 dz4 = *(const float4*)(vf + base);
    const float4 dy4 = *(const float4*)(vf + NVOX + base);
    const float4 dx4 = *(const float4*)(vf + 2 * NVOX + base);
    const float4 f4  = *(const float4*)(fix + base);
    const int4   m4  = *(const int4*)(mask + base);

    const float dzv[4] = {dz4.x, dz4.y, dz4.z, dz4.w};
    const float dyv[4] = {dy4.x, dy4.y, dy4.z, dy4.w};
    const float dxv[4] = {dx4.x, dx4.y, dx4.z, dx4.w};
    const float fv[4]  = {f4.x, f4.y, f4.z, f4.w};
    const int   mv[4]  = {m4.x, m4.y, m4.z, m4.w};

    float sq = 0.0f, cnt = 0.0f;

    #pragma unroll
    for (int j = 0; j < 4; ++j) {
        const float z = (float)gz + dzv[j];
        const float y = (float)gy + dyv[j];
        const float x = (float)(gx0 + j) + dxv[j];

        const float z0f = floorf(z), y0f = floorf(y), x0f = floorf(x);
        const float wz = z - z0f, wy = y - y0f, wx = x - x0f;
        const int z0 = (int)z0f, y0 = (int)y0f, x0 = (int)x0f;

        const int z0l = z0 - z_lo, y0l = y0 - y_lo, x0l = x0 - x_lo;
        const bool inbox = ((unsigned)z0l < RSZ - 1) & ((unsigned)y0l < RSY - 1) &
                           ((unsigned)x0l < RSX - 1);

        float v000, v001, v010, v011, v100, v101, v110, v111;
        if (inbox) {
            const int o = z0l * SLAB + y0l * RSX + x0l;
            v000 = __half2float(smov[o]);
            v001 = __half2float(smov[o + 1]);
            v010 = __half2float(smov[o + RSX]);
            v011 = __half2float(smov[o + RSX + 1]);
            v100 = __half2float(smov[o + SLAB]);
            v101 = __half2float(smov[o + SLAB + 1]);
            v110 = __half2float(smov[o + SLAB + RSX]);
            v111 = __half2float(smov[o + SLAB + RSX + 1]);
        } else {
            // rare: displacement beyond halo — full-precision global fallback
            const int z1 = z0 + 1, y1 = y0 + 1, x1 = x0 + 1;
            const bool zi0 = (unsigned)z0 < DD, zi1 = (unsigned)z1 < DD;
            const bool yi0 = (unsigned)y0 < HH, yi1 = (unsigned)y1 < HH;
            const bool xi0 = (unsigned)x0 < WW, xi1 = (unsigned)x1 < WW;
            auto ld = [&](int iz, int iy, int ix, bool ok) -> float {
                return ok ? mov[(iz * HH + iy) * WW + ix] : 0.0f;
            };
            v000 = ld(z0, y0, x0, zi0 & yi0 & xi0);
            v001 = ld(z0, y0, x1, zi0 & yi0 & xi1);
            v010 = ld(z0, y1, x0, zi0 & yi1 & xi0);
            v011 = ld(z0, y1, x1, zi0 & yi1 & xi1);
            v100 = ld(z1, y0, x0, zi1 & yi0 & xi0);
            v101 = ld(z1, y0, x1, zi1 & yi0 & xi1);
            v110 = ld(z1, y1, x0, zi1 & yi1 & xi0);
            v111 = ld(z1, y1, x1, zi1 & yi1 & xi1);
        }

        const float c00 = v000 + (v001 - v000) * wx;
        const float c01 = v010 + (v011 - v010) * wx;
        const float c10 = v100 + (v101 - v100) * wx;
        const float c11 = v110 + (v111 - v110) * wx;
        const float c0 = c00 + (c01 - c00) * wy;
        const float c1 = c10 + (c11 - c10) * wy;
        const float warped = c0 + (c1 - c0) * wz;

        const float m = (mv[j] != 0) ? 1.0f : 0.0f;
        const float diff = warped - fv[j];
        sq += diff * diff * m;
        cnt += m;
    }

    // ---- reduction: wave64 shuffle -> LDS -> one atomic pair per block ----
    #pragma unroll
    for (int off = 32; off > 0; off >>= 1) {
        sq  += __shfl_down(sq, off, 64);
        cnt += __shfl_down(cnt, off, 64);
    }
    const int lane = tid & 63;
    const int wid = tid >> 6;              // 0..7
    if (lane == 0) { s_sq[wid] = sq; s_cnt[wid] = cnt; }
    __syncthreads();
    if (tid == 0) {
        float bsq = 0.0f, bcnt = 0.0f;
        #pragma unroll
        for (int i = 0; i < 8; ++i) { bsq += s_sq[i]; bcnt += s_cnt[i]; }
        atomicAdd(&acc[0], bsq);
        atomicAdd(&acc[1], bcnt);
        __threadfence();
        const unsigned old = atomicAdd((unsigned*)&acc[2], 1u);
        if (old == NBLK - 1) {
            __threadfence();
            const float s = atomicAdd(&acc[0], 0.0f);   // coherent read
            const float c = atomicAdd(&acc[1], 0.0f);
            out[0] = s / fmaxf(c, 1.0f);
        }
    }
}

extern "C" void kernel_launch(void* const* d_in, const int* in_sizes, int n_in,
                              void* d_out, int out_size, void* d_ws, size_t ws_size,
                              hipStream_t stream) {
    const float* mov  = (const float*)d_in[0];
    const float* vf   = (const float*)d_in[1];
    const float* fix  = (const float*)d_in[2];
    const int*   mask = (const int*)d_in[3];
    float* acc = (float*)d_ws;
    float* out = (float*)d_out;

    hipMemsetAsync(d_ws, 0, 4 * sizeof(float), stream);

    dim3 grid(WW / TX, HH / TY, DD / TZ);  // 12 x 12 x 24 = 3456 blocks
    warp_mse_tiled<<<grid, NTHREADS, 0, stream>>>(mov, vf, fix, mask, acc, out);
}

// Round 5
// 281.556 us; speedup vs baseline: 1.5100x; 1.5100x over previous
//
#include <hip/hip_runtime.h>

#define DD 192
#define HH 192
#define WW 192
#define NVOX (DD * HH * WW)

#define TS 16                // tile edge
#define RSX 32               // x: [-8, +24)  (halo 8 low / 7 high + corner)
#define RSY 33               // y: [-8, +25)
#define RSZ 33               // z: [-8, +25)
#define ROW RSX              // 32 floats per row (pow2)
#define SLAB (RSY * RSX)     // 1056 floats per z-slab
#define RTOT (RSZ * SLAB)    // 34848 floats = 139392 B
#define NT 1024
#define NQ4 (RTOT / 4)       // 8712 float4 chunks
#define Q4_PER_SLAB (SLAB / 4)   // 264
#define NBLK (12 * 12 * 12)

#define AS1 __attribute__((address_space(1)))
#define AS3 __attribute__((address_space(3)))

__global__ __launch_bounds__(NT) void warp_mse(
    const float* __restrict__ mov,
    const float* __restrict__ vf,
    const float* __restrict__ fix,
    const int* __restrict__ mask,
    float* __restrict__ acc,   // acc[0]=sum(sq*m), acc[1]=sum(m), acc[2]=done ctr
    float* __restrict__ out)
{
    __shared__ float smov[RTOT];
    __shared__ float s_sq[16], s_cnt[16];

    const int tid = threadIdx.x;
    const int bx0 = blockIdx.x * TS, by0 = blockIdx.y * TS, bz0 = blockIdx.z * TS;
    const int x_lo = bx0 - 8, y_lo = by0 - 8, z_lo = bz0 - 8;

    // ---- prefetch compute inputs (consumed after the staging barrier) ----
    const int lxg = (tid & 3) * 4;
    const int ly  = (tid >> 2) & 15;
    const int lz  = tid >> 6;
    const int gz = bz0 + lz, gy = by0 + ly, gx0 = bx0 + lxg;
    const int base = (gz * HH + gy) * WW + gx0;
    const float4 dz4 = *(const float4*)(vf + base);
    const float4 dy4 = *(const float4*)(vf + NVOX + base);
    const float4 dx4 = *(const float4*)(vf + 2 * NVOX + base);
    const float4 f4  = *(const float4*)(fix + base);
    const int4   m4  = *(const int4*)(mask + base);

    // ---- edge blocks: pre-zero LDS (masked-off DMA lanes leave zeros) ----
    const bool edge = (blockIdx.x == 0) | (blockIdx.x == 11) |
                      (blockIdx.y == 0) | (blockIdx.y == 11) |
                      (blockIdx.z == 0) | (blockIdx.z == 11);
    if (edge) {
        float4* s4 = (float4*)smov;
        #pragma unroll
        for (int i = 0; i < 9; ++i) {
            const int q = tid + i * NT;
            if (q < NQ4) s4[q] = make_float4(0.f, 0.f, 0.f, 0.f);
        }
        __syncthreads();
    }

    // ---- async stage mov region: global_load_lds width=16 ----
    // Each lane loads one float4; HW writes LDS at wave_base + laneid*16,
    // which matches q = qb + laneid exactly. OOB lanes are exec-masked out.
    #pragma unroll
    for (int i = 0; i < 9; ++i) {
        const int q = tid + i * NT;
        if (q < NQ4) {
            const int rz = q / Q4_PER_SLAB;
            const int rem = q - rz * Q4_PER_SLAB;
            const int ry = rem >> 3;          // 8 float4 per 32-float row
            const int k  = rem & 7;
            const int gzs = z_lo + rz, gys = y_lo + ry, gxs = x_lo + 4 * k;
            // x OOB is float4-granular (offsets are multiples of 4)
            const bool valid = ((unsigned)gzs < DD) & ((unsigned)gys < HH) &
                               ((unsigned)gxs < WW);
            const int qb = i * NT + (tid & ~63);   // wave-uniform float4 base
            if (valid) {
                __builtin_amdgcn_global_load_lds(
                    (AS1 void*)(mov + ((gzs * HH + gys) * WW + gxs)),
                    (AS3 void*)(smov + 4 * qb), 16, 0, 0);
            }
        }
    }
    __syncthreads();   // drains vmcnt -> staging complete

    // ---- compute: each thread handles an x-quad of 4 voxels ----
    const float dzv[4] = {dz4.x, dz4.y, dz4.z, dz4.w};
    const float dyv[4] = {dy4.x, dy4.y, dy4.z, dy4.w};
    const float dxv[4] = {dx4.x, dx4.y, dx4.z, dx4.w};
    const float fv[4]  = {f4.x, f4.y, f4.z, f4.w};
    const int   mv[4]  = {m4.x, m4.y, m4.z, m4.w};

    float sq = 0.0f, cnt = 0.0f;

    #pragma unroll
    for (int j = 0; j < 4; ++j) {
        const float z = (float)gz + dzv[j];
        const float y = (float)gy + dyv[j];
        const float x = (float)(gx0 + j) + dxv[j];

        const float z0f = floorf(z), y0f = floorf(y), x0f = floorf(x);
        const float wz = z - z0f, wy = y - y0f, wx = x - x0f;
        const int z0 = (int)z0f, y0 = (int)y0f, x0 = (int)x0f;

        const int z0l = z0 - z_lo, y0l = y0 - y_lo, x0l = x0 - x_lo;
        const bool inbox = ((unsigned)z0l < RSZ - 1) & ((unsigned)y0l < RSY - 1) &
                           ((unsigned)x0l < RSX - 1);

        float v000, v001, v010, v011, v100, v101, v110, v111;
        if (inbox) {
            const int o = z0l * SLAB + y0l * ROW + x0l;
            v000 = smov[o];
            v001 = smov[o + 1];
            v010 = smov[o + ROW];
            v011 = smov[o + ROW + 1];
            v100 = smov[o + SLAB];
            v101 = smov[o + SLAB + 1];
            v110 = smov[o + SLAB + ROW];
            v111 = smov[o + SLAB + ROW + 1];
        } else {
            // rare: displacement beyond halo — global fallback
            const int z1 = z0 + 1, y1 = y0 + 1, x1 = x0 + 1;
            const bool zi0 = (unsigned)z0 < DD, zi1 = (unsigned)z1 < DD;
            const bool yi0 = (unsigned)y0 < HH, yi1 = (unsigned)y1 < HH;
            const bool xi0 = (unsigned)x0 < WW, xi1 = (unsigned)x1 < WW;
            auto ld = [&](int iz, int iy, int ix, bool ok) -> float {
                return ok ? mov[(iz * HH + iy) * WW + ix] : 0.0f;
            };
            v000 = ld(z0, y0, x0, zi0 & yi0 & xi0);
            v001 = ld(z0, y0, x1, zi0 & yi0 & xi1);
            v010 = ld(z0, y1, x0, zi0 & yi1 & xi0);
            v011 = ld(z0, y1, x1, zi0 & yi1 & xi1);
            v100 = ld(z1, y0, x0, zi1 & yi0 & xi0);
            v101 = ld(z1, y0, x1, zi1 & yi0 & xi1);
            v110 = ld(z1, y1, x0, zi1 & yi1 & xi0);
            v111 = ld(z1, y1, x1, zi1 & yi1 & xi1);
        }

        const float c00 = v000 + (v001 - v000) * wx;
        const float c01 = v010 + (v011 - v010) * wx;
        const float c10 = v100 + (v101 - v100) * wx;
        const float c11 = v110 + (v111 - v110) * wx;
        const float c0 = c00 + (c01 - c00) * wy;
        const float c1 = c10 + (c11 - c10) * wy;
        const float warped = c0 + (c1 - c0) * wz;

        const float m = (mv[j] != 0) ? 1.0f : 0.0f;
        const float diff = warped - fv[j];
        sq += diff * diff * m;
        cnt += m;
    }

    // ---- reduction: wave64 shuffle -> LDS -> one atomic pair per block ----
    #pragma unroll
    for (int off = 32; off > 0; off >>= 1) {
        sq  += __shfl_down(sq, off, 64);
        cnt += __shfl_down(cnt, off, 64);
    }
    const int lane = tid & 63;
    const int wid = tid >> 6;
    if (lane == 0) { s_sq[wid] = sq; s_cnt[wid] = cnt; }
    __syncthreads();
    if (tid == 0) {
        float bsq = 0.0f, bcnt = 0.0f;
        #pragma unroll
        for (int i = 0; i < 16; ++i) { bsq += s_sq[i]; bcnt += s_cnt[i]; }
        atomicAdd(&acc[0], bsq);
        atomicAdd(&acc[1], bcnt);
        __threadfence();
        const unsigned old = atomicAdd((unsigned*)&acc[2], 1u);
        if (old == NBLK - 1) {
            __threadfence();
            const float s = atomicAdd(&acc[0], 0.0f);   // coherent read
            const float c = atomicAdd(&acc[1], 0.0f);
            out[0] = s / fmaxf(c, 1.0f);
        }
    }
}

extern "C" void kernel_launch(void* const* d_in, const int* in_sizes, int n_in,
                              void* d_out, int out_size, void* d_ws, size_t ws_size,
                              hipStream_t stream) {
    const float* mov  = (const float*)d_in[0];
    const float* vf   = (const float*)d_in[1];
    const float* fix  = (const float*)d_in[2];
    const int*   mask = (const int*)d_in[3];
    float* acc = (float*)d_ws;
    float* out = (float*)d_out;

    hipMemsetAsync(d_ws, 0, 4 * sizeof(float), stream);

    dim3 grid(WW / TS, HH / TS, DD / TS);  // 12 x 12 x 12 = 1728 blocks
    warp_mse<<<grid, NT, 0, stream>>>(mov, vf, fix, mask, acc, out);
}